// Round 1
// 443.945 us; speedup vs baseline: 1.0578x; 1.0578x over previous
//
#include <hip/hip_runtime.h>

#define EPS 1e-5f
#define WPB 4  // waves (rays) per 256-thread block

// DPP move with old=0: masked-out rows / OOB lanes return 0 (identity for sum
// and for max over non-negative values).
template<int CTRL, int RM>
__device__ __forceinline__ float dppf(float v) {
    return __int_as_float(__builtin_amdgcn_update_dpp(
        0, __float_as_int(v), CTRL, RM, 0xf, true));
}
template<int CTRL, int RM>
__device__ __forceinline__ int dppi(int v) {
    return __builtin_amdgcn_update_dpp(0, v, CTRL, RM, 0xf, true);
}

__device__ __forceinline__ float readlane_f(float v, int l) {
    return __int_as_float(__builtin_amdgcn_readlane(__float_as_int(v), l));
}

// wave-private LDS ordering fence (all sharing is intra-wave; no s_barrier needed)
__device__ __forceinline__ void lds_fence() {
    asm volatile("s_waitcnt lgkmcnt(0)" ::: "memory");
}

// Inclusive 64-lane sum-scan: 4 row_shr steps + row_bcast15/31 cross-row finish.
// No readlanes, no select chains (canonical GCN wave64 scan).
__device__ __forceinline__ float wave_scan_sum(float x) {
    x += dppf<0x111, 0xf>(x);   // row_shr:1
    x += dppf<0x112, 0xf>(x);   // row_shr:2
    x += dppf<0x114, 0xf>(x);   // row_shr:4
    x += dppf<0x118, 0xf>(x);   // row_shr:8  -> inclusive within 16-lane row
    x += dppf<0x142, 0xa>(x);   // row_bcast15, rows 1 & 3 += prev-row total
    x += dppf<0x143, 0xc>(x);   // row_bcast31, rows 2 & 3 += lanes0-31 total
    return x;
}

// Inclusive 64-lane max-scan (values >= 0)
__device__ __forceinline__ int wave_scan_max(int x) {
    x = max(x, dppi<0x111, 0xf>(x));
    x = max(x, dppi<0x112, 0xf>(x));
    x = max(x, dppi<0x114, 0xf>(x));
    x = max(x, dppi<0x118, 0xf>(x));
    x = max(x, dppi<0x142, 0xa>(x));
    x = max(x, dppi<0x143, 0xc>(x));
    return x;
}

// One 64-lane wave per ray; lane i holds z[i], w[i]. No __syncthreads anywhere.
__global__ __launch_bounds__(256) void ray_refine_kernel(
    const float* __restrict__ lengths,      // [n_rays, 64]
    const float* __restrict__ ray_weights,  // [n_rays, 64]
    float* __restrict__ out,                // [n_rays, 128]
    int n_rays)
{
    const int lane = threadIdx.x & 63;
    const int wid  = threadIdx.x >> 6;
    int ray = blockIdx.x * WPB + wid;
    if (ray >= n_rays) ray = n_rays - 1;

    // stride-1 per-lane layout: bank = lane%32 -> 2-way (free). The previous
    // [64][2] int layout was an 8B lane stride -> 4-way conflict on every access.
    __shared__ float sZ[WPB][64];      // z values
    __shared__ float sC[WPB][64];      // cdf values (entries 0..62 valid)
    __shared__ int   sInd[WPB][64];    // ind scatter slots
    __shared__ int   sRank[WPB][64];   // rank scatter slots

    const size_t base = (size_t)ray * 64;
    const float z  = lengths[base + lane];
    const float wf = ray_weights[base + lane];

    // cdf_k = (sum_{i<k} w_i)/total where w_i = ray_weights[i+1]+eps, i in [0,62).
    // Map: lane k's scan input = w_{k-1} = wf[k]+eps for k in [1,62]; 0 otherwise.
    // Then inclusive-scan(lane k) = total*cdf_k, and scan(lane 62) = total.
    float win = (lane >= 1 && lane <= 62) ? (wf + EPS) : 0.0f;
    float x = wave_scan_sum(win);
    const float total = readlane_f(x, 62);
    const float inv_total = __builtin_amdgcn_rcpf(total);  // 1 ulp, tolerance-safe
    const float cv = x * inv_total;    // cdf value at this lane (valid for lane<63)

    sZ[wid][lane]    = z;
    sC[wid][lane]    = cv;
    sInd[wid][lane]  = 0;
    sRank[wid][lane] = 0;
    lds_fence();

    // --- inverse-CDF sample index via scatter + max-scan ---
    // m_k = smallest j with cv*63 <= j  ==  ceil(cv*63)  (v_ceil is exact).
    // Integer-grid comparison instead of cv <= j/63: tie-zone shifts only, and
    // the interpolant is continuous at bin boundaries (segment k @t=1 == segment
    // k+1 @t=0 == mids[k]), so any tie flip perturbs the sample by O(ulp).
    const int m = (int)ceilf(cv * 63.0f);           // in [0, 64]; cv >= 0 always
    if (lane < 63 && m < 64) atomicMax(&sInd[wid][m], lane + 1);
    lds_fence();

    // ind_j = #{k: m_k <= j} = max-scan of scattered (k+1)   (m_k non-decreasing)
    const int ind = wave_scan_max(sInd[wid][lane]);           // in [1,63]
    const int below = ind - 1;                                 // in [0,62]
    const int above = min(ind, 62);

    const float cb  = sC[wid][below];
    const float ca  = sC[wid][above];
    const float zb  = sZ[wid][below];
    const float zb1 = sZ[wid][below + 1];
    const float za  = sZ[wid][above];
    const float za1 = sZ[wid][above + 1];
    const float bb = 0.5f * (zb + zb1);    // mids[below]
    const float ba = 0.5f * (za + za1);    // mids[above]
    const float denom = ca - cb;
    const float rden = (denom < EPS) ? 1.0f : __builtin_amdgcn_rcpf(denom);
    const float u = (lane >= 63) ? 1.0f : (float)lane * (1.0f / 63.0f);
    const float t = (u - cb) * rden;
    const float s = bb + t * (ba - bb);    // fine sample, in (z[below], z[above+1])

    // rank of sample among z: structurally r in {below+1, below+2}
    const int r = below + 1 + ((above > below && zb1 <= s) ? 1 : 0);   // in [1,63]

    // rank of z among samples: cntB_i = #{j: r_j <= i} via scatter + max-scan
    atomicMax(&sRank[wid][r], lane + 1);
    lds_fence();
    const int cntB = wave_scan_max(sRank[wid][lane]);

    // merged positions (valid permutation: z-before-sample tie-break both ways)
    const size_t ob = (size_t)ray * 128;
    out[ob + lane + cntB] = z;   // pos = i + #{samples < z_i}
    out[ob + lane + r]    = s;   // pos = j + #{z <= sample_j}
}

extern "C" void kernel_launch(void* const* d_in, const int* in_sizes, int n_in,
                              void* d_out, int out_size, void* d_ws, size_t ws_size,
                              hipStream_t stream) {
    // inputs (setup_inputs order): origins, directions, lengths, xys, ray_weights
    const float* lengths     = (const float*)d_in[2];
    const float* ray_weights = (const float*)d_in[4];
    float* out = (float*)d_out;

    const int n_rays = in_sizes[2] / 64;
    const int grid = (n_rays + WPB - 1) / WPB;
    ray_refine_kernel<<<grid, 256, 0, stream>>>(lengths, ray_weights, out, n_rays);
}